// Round 18
// baseline (304.856 us; speedup 1.0000x reference)
//
#include <hip/hip_runtime.h>
#include <hip/hip_bf16.h>
#include <stdint.h>

#define SEQ 2048
#define HIDDEN 4096
#define NHEADS 32
#define HD 128
#define QKV_LD 6144
#define OUT_LD 4096

typedef __attribute__((ext_vector_type(8))) short short8;
typedef __attribute__((ext_vector_type(4))) short short4v;
typedef __attribute__((ext_vector_type(4))) float f32x4;
typedef __attribute__((ext_vector_type(4))) int int4v;
typedef __attribute__((ext_vector_type(2))) unsigned int uint2v;
typedef __attribute__((ext_vector_type(4))) float float4v;

__device__ __forceinline__ short f2bf(float f) {
  uint32_t u = __builtin_bit_cast(uint32_t, f);
  u += 0x7fff + ((u >> 16) & 1);   // RNE
  return (short)(u >> 16);
}

// ---------------- cast fp32 -> bf16 ----------------
__global__ void cast_kernel(const float* __restrict__ in, short* __restrict__ out, int n4) {
  int stride = gridDim.x * blockDim.x;
  for (int i = blockIdx.x * blockDim.x + threadIdx.x; i < n4; i += stride) {
    float4v v = ((const float4v*)in)[i];
    short4v o;
    o[0] = f2bf(v[0]); o[1] = f2bf(v[1]); o[2] = f2bf(v[2]); o[3] = f2bf(v[3]);
    ((short4v*)out)[i] = o;
  }
}

// ======== 256 x (64*NBF) GEMM, 2-barrier K-tile: C = A[M][K] * B[N][K]^T ========
// 512 thr = 8 waves (2M x 4N). BK=64, double-buffered LDS, chunk^=row&7 swizzle.
// XCD map: each XCD owns NT/8 nt-columns x all 8 mt (mt-fast) -> B panel stays
// L2-resident; only A streams.
template <typename OT, int NBF>
__global__ __launch_bounds__(512, 2) void gemm256b(const short* __restrict__ A,
                                                   const short* __restrict__ B,
                                                   OT* __restrict__ C,
                                                   int M, int N, int K, int NT) {
  __shared__ __align__(16) short lds[32768 + NBF * 8192];  // A: 2x16384, B: 2x NBF*4096
  const int tid = threadIdx.x;
  const int w = tid >> 6, lane = tid & 63;
  const int wr = w >> 2, wc = w & 3;
  const int llo = lane & 15, lhi = lane >> 4;

  const int xcd = (int)blockIdx.x & 7;
  const int i = (int)blockIdx.x >> 3;
  const int nt = xcd * (NT >> 3) + (i >> 3);
  const int mt = i & 7;
  const size_t arow0 = (size_t)mt * 256, brow0 = (size_t)nt * (NBF * 64);
  const short* Ab = A + arow0 * K;
  const short* Bb = B + brow0 * K;

  f32x4 acc[8][NBF] = {};

  auto STAGE_A = [&](int kt, int j) {
    const int bufd = kt & 1;
    const int r0 = (j << 6) + (w << 3);
    const int row = r0 + (lane >> 3);
    const short* src = Ab + (size_t)row * K + (kt << 6) + (((lane & 7) ^ (row & 7)) << 3);
    short* dst = lds + (bufd << 14) + r0 * 64;
    __builtin_amdgcn_global_load_lds(
        (const __attribute__((address_space(1))) uint32_t*)src,
        (__attribute__((address_space(3))) uint32_t*)dst, 16, 0, 0);
  };
  auto STAGE_B = [&](int kt, int j) {
    const int bufd = kt & 1;
    const int r0 = (j << 6) + (w << 3);
    const int row = r0 + (lane >> 3);
    const short* src = Bb + (size_t)row * K + (kt << 6) + (((lane & 7) ^ (row & 7)) << 3);
    short* dst = lds + 32768 + bufd * (NBF << 12) + r0 * 64;
    __builtin_amdgcn_global_load_lds(
        (const __attribute__((address_space(1))) uint32_t*)src,
        (__attribute__((address_space(3))) uint32_t*)dst, 16, 0, 0);
  };
  auto STAGE = [&](int kt) {
#pragma unroll
    for (int j = 0; j < 4; j++) STAGE_A(kt, j);
#pragma unroll
    for (int j = 0; j < NBF; j++) STAGE_B(kt, j);
  };

  auto LDA = [&](int bufd, int m, int kk) -> short8 {
    const int row = (wr << 7) + (m << 4) + llo;
    const int ch = ((kk << 2) + lhi) ^ (row & 7);
    return *(const short8*)(lds + (bufd << 14) + row * 64 + (ch << 3));
  };
  auto LDB = [&](int bufd, int n, int kk) -> short8 {
    const int row = wc * (NBF << 4) + (n << 4) + llo;
    const int ch = ((kk << 2) + lhi) ^ (row & 7);
    return *(const short8*)(lds + 32768 + bufd * (NBF << 12) + row * 64 + (ch << 3));
  };

  STAGE(0);
  STAGE(1);
  if constexpr (NBF == 3) asm volatile("s_waitcnt vmcnt(7)" ::: "memory");
  else                    asm volatile("s_waitcnt vmcnt(6)" ::: "memory");
  __builtin_amdgcn_s_barrier();

  const int NKT = K >> 6;
  for (int kt = 0; kt < NKT; ++kt) {
    const int bufd = kt & 1;
    short8 b_[NBF][2];
#pragma unroll
    for (int n = 0; n < NBF; n++) { b_[n][0] = LDB(bufd, n, 0); b_[n][1] = LDB(bufd, n, 1); }
#pragma unroll
    for (int m = 0; m < 8; m++) {
      short8 a0 = LDA(bufd, m, 0);
      short8 a1 = LDA(bufd, m, 1);
#pragma unroll
      for (int n = 0; n < NBF; n++) {
        acc[m][n] = __builtin_amdgcn_mfma_f32_16x16x32_bf16(a0, b_[n][0], acc[m][n], 0, 0, 0);
        acc[m][n] = __builtin_amdgcn_mfma_f32_16x16x32_bf16(a1, b_[n][1], acc[m][n], 0, 0, 0);
      }
    }
    asm volatile("s_waitcnt lgkmcnt(0)" ::: "memory");
    __builtin_amdgcn_s_barrier();            // all waves done reading bufd
    if (kt + 2 < NKT) STAGE(kt + 2);         // refill this buffer
    if (kt + 1 < NKT) {
      if (kt + 2 < NKT) {
        if constexpr (NBF == 3) asm volatile("s_waitcnt vmcnt(7)" ::: "memory");
        else                    asm volatile("s_waitcnt vmcnt(6)" ::: "memory");
      } else {
        asm volatile("s_waitcnt vmcnt(0)" ::: "memory");
      }
      __builtin_amdgcn_s_barrier();          // next tile's data visible
    }
  }

#pragma unroll
  for (int m = 0; m < 8; m++)
#pragma unroll
    for (int n = 0; n < NBF; n++)
#pragma unroll
      for (int r = 0; r < 4; r++) {
        const size_t row = arow0 + (wr << 7) + (m << 4) + (lhi << 2) + r;
        const size_t col = brow0 + wc * (NBF << 4) + (n << 4) + llo;
        const float v = acc[m][n][r];
        if constexpr (sizeof(OT) == 2) C[row * N + col] = f2bf(v);
        else                           C[row * N + col] = v;
      }
}

// ---------------- flash attention, causal GQA, KVBLK=128 ----------------
// R17 base + pipelined PV: two register slabs (vrA/vrB), tr-reads for slab
// k+2 issued right after MFMA of slab k, gated by counted lgkmcnt(15)
// (in-order DS completion => older 16-slab landed). pa/P DS ops drained
// before the ladder so the count ledger holds only the asm tr-reads.
__global__ __launch_bounds__(512) void attn_fwd(const short* __restrict__ qkv,
                                                short* __restrict__ aout) {
  const int qt = gridDim.y - 1 - blockIdx.y;          // heavy blocks first
  const int h = blockIdx.x;
  const int kvh = h >> 2, g = h & 3;
  const int tid = threadIdx.x;
  const int wave = tid >> 6, lane = tid & 63;
  const int lhi = lane >> 4, llo = lane & 15;

  __shared__ __align__(16) short Ksm[2][128 * 128];  // XOR-swizzled (chunk ^= row&7)
  __shared__ __align__(16) short Vsm[128 * 128];     // subtiled [k/4][d/16][4][16]
  __shared__ __align__(16) short Psm[8][16 * 136];   // per-wave P, stride 136

  const float scale2 = 0.08838834764831845f * 1.4426950408889634f;  // 1/sqrt(128)*log2e

  const int qrow = qt * 128 + wave * 16 + llo;
  const short* qbase = qkv + (size_t)qrow * QKV_LD + (kvh * 6 + g) * HD;
  short8 qf[4];
#pragma unroll
  for (int kk = 0; kk < 4; kk++) qf[kk] = *(const short8*)(qbase + kk * 32 + lhi * 8);

  f32x4 o[8] = {};
  float mrow[4], lrow[4];
#pragma unroll
  for (int r = 0; r < 4; r++) { mrow[r] = -1e30f; lrow[r] = 0.f; }

  const short* Kg = qkv + (kvh * 6 + 4) * HD;
  const short* Vg = qkv + (kvh * 6 + 5) * HD;

  auto STAGE_K = [&](int t, int buf) {               // 128x128 bf16 = 32KB = 32 calls
#pragma unroll
    for (int c = 0; c < 4; c++) {
      const int call = wave * 4 + c;
      const int row = call * 4 + lhi;
      const int sc = llo ^ (row & 7);
      __builtin_amdgcn_global_load_lds(
          (const __attribute__((address_space(1))) uint32_t*)(Kg + (size_t)(t * 128 + row) * QKV_LD + sc * 8),
          (__attribute__((address_space(3))) uint32_t*)(&Ksm[buf][0] + call * 512), 16, 0, 0);
    }
  };
  short8 vreg[4];
  auto LOAD_V = [&](int t) {                         // 128 rows -> 4 short8/thread
#pragma unroll
    for (int c = 0; c < 4; c++) {
      const int idx = c * 512 + tid;
      const int vr = idx >> 4;
      vreg[c] = *(const short8*)(Vg + (size_t)(t * 128 + vr) * QKV_LD + (idx & 15) * 8);
    }
  };
  auto WRITE_V = [&]() {
#pragma unroll
    for (int c = 0; c < 4; c++) {
      const int idx = c * 512 + tid;
      const int vr = idx >> 4, vc = idx & 15;
      *(short8*)(&Vsm[0] + ((vr >> 2) * 8 + (vc >> 1)) * 64 + (vr & 3) * 16 + (vc & 1) * 8) = vreg[c];
    }
  };

  const uint32_t vlane0 = (uint32_t)(uintptr_t)(__attribute__((address_space(3))) short*)(&Vsm[0])
                          + (uint32_t)(lhi * 2048 + llo * 8);

  // prologue: K(0) DMA + V(0) regs -> commit V(0); all visible after barrier
  STAGE_K(0, 0);
  LOAD_V(0);
  asm volatile("s_waitcnt vmcnt(0)" ::: "memory");
  WRITE_V();
  __syncthreads();

  const int ntiles = qt + 1;
  const int qpos0 = qt * 128 + wave * 16 + lhi * 4;   // + r
  for (int t = 0; t < ntiles; t++) {
    const int cur = t & 1, nxt = cur ^ 1;
    const bool pf = (t + 1 < ntiles);
    if (pf) { LOAD_V(t + 1); STAGE_K(t + 1, nxt); }  // in flight across whole tile

    // S = Q K^T from Ksm[cur] (128 cols)
    const short* Kc = &Ksm[cur][0];
    f32x4 s[8] = {};
#pragma unroll
    for (int n = 0; n < 8; n++) {
#pragma unroll
      for (int kk = 0; kk < 4; kk++) {
        const int krow = n * 16 + llo;
        const int ch = (kk * 4 + lhi) ^ (krow & 7);
        short8 kf = *(const short8*)(Kc + krow * 128 + ch * 8);
        s[n] = __builtin_amdgcn_mfma_f32_16x16x32_bf16(qf[kk], kf, s[n], 0, 0, 0);
      }
    }

    float sv[8][4];
    if (t == qt) {   // diagonal tile: causal mask (wave-uniform branch)
#pragma unroll
      for (int n = 0; n < 8; n++)
#pragma unroll
        for (int r = 0; r < 4; r++) {
          float x = s[n][r] * scale2;
          if (t * 128 + n * 16 + llo > qpos0 + r) x = -1e30f;
          sv[n][r] = x;
        }
    } else {
#pragma unroll
      for (int n = 0; n < 8; n++)
#pragma unroll
        for (int r = 0; r < 4; r++) sv[n][r] = s[n][r] * scale2;
    }

    // online softmax with defer-max
    float rm4[4];
#pragma unroll
    for (int r = 0; r < 4; r++) {
      float rm = sv[0][r];
#pragma unroll
      for (int n = 1; n < 8; n++) rm = fmaxf(rm, sv[n][r]);
#pragma unroll
      for (int msk = 1; msk < 16; msk <<= 1) rm = fmaxf(rm, __shfl_xor(rm, msk));
      rm4[r] = rm;
    }
    bool need = false;
#pragma unroll
    for (int r = 0; r < 4; r++) need = need || (rm4[r] > mrow[r] + 8.0f);
    if (__any(need)) {
#pragma unroll
      for (int r = 0; r < 4; r++) {
        const float mnew = fmaxf(mrow[r], rm4[r]);
        const float a = exp2f(mrow[r] - mnew);
        mrow[r] = mnew;
        lrow[r] *= a;
#pragma unroll
        for (int nn = 0; nn < 8; nn++) o[nn][r] *= a;
      }
    }
#pragma unroll
    for (int r = 0; r < 4; r++) {
      float rs = 0.f;
#pragma unroll
      for (int n = 0; n < 8; n++) {
        float p = exp2f(sv[n][r] - mrow[r]);
        sv[n][r] = p;
        rs += p;
      }
#pragma unroll
      for (int msk = 1; msk < 16; msk <<= 1) rs += __shfl_xor(rs, msk);
      lrow[r] += rs;
    }

    // P -> LDS (wave-local), A-frags back
    short* P = &Psm[wave][0];
#pragma unroll
    for (int n = 0; n < 8; n++)
#pragma unroll
      for (int r = 0; r < 4; r++)
        P[(lhi * 4 + r) * 136 + n * 16 + llo] = f2bf(sv[n][r]);
    short8 pa[4];
#pragma unroll
    for (int ks = 0; ks < 4; ks++)
      pa[ks] = *(const short8*)(P + llo * 136 + ks * 32 + lhi * 8);

    // drain pa reads + P writes so only asm tr-reads occupy the DS queue
    asm volatile("s_waitcnt lgkmcnt(0)" ::: "memory");
    __builtin_amdgcn_sched_barrier(0);

    // PV: pipelined slabs. ISSUE(buf, ks) = 16 tr-reads; PVMM consumes.
    uint2v vrA[8][2], vrB[8][2];
    auto ISSUE = [&](uint2v (&buf)[8][2], int ks) {
#pragma unroll
      for (int nn = 0; nn < 8; nn++)
#pragma unroll
        for (int hh = 0; hh < 2; hh++) {
          asm volatile("ds_read_b64_tr_b16 %0, %1 offset:%2"
                       : "=v"(buf[nn][hh])
                       : "v"(vlane0), "i"(ks * 8192 + hh * 1024 + nn * 128));
        }
    };
    auto PVMM = [&](uint2v (&buf)[8][2], int ks) {
#pragma unroll
      for (int nn = 0; nn < 8; nn++) {
        int4v tv;
        tv[0] = (int)buf[nn][0][0]; tv[1] = (int)buf[nn][0][1];
        tv[2] = (int)buf[nn][1][0]; tv[3] = (int)buf[nn][1][1];
        o[nn] = __builtin_amdgcn_mfma_f32_16x16x32_bf16(pa[ks], __builtin_bit_cast(short8, tv), o[nn], 0, 0, 0);
      }
    };

    ISSUE(vrA, 0);
    ISSUE(vrB, 1);                                   // 32 outstanding
    asm volatile("s_waitcnt lgkmcnt(15)" ::: "memory");  // slab0 landed (in-order)
    __builtin_amdgcn_sched_barrier(0);
    PVMM(vrA, 0);
    ISSUE(vrA, 2);
    asm volatile("s_waitcnt lgkmcnt(15)" ::: "memory");  // slab1 landed
    __builtin_amdgcn_sched_barrier(0);
    PVMM(vrB, 1);
    ISSUE(vrB, 3);
    asm volatile("s_waitcnt lgkmcnt(15)" ::: "memory");  // slab2 landed
    __builtin_amdgcn_sched_barrier(0);
    PVMM(vrA, 2);
    asm volatile("s_waitcnt lgkmcnt(0)" ::: "memory");   // slab3 landed
    __builtin_amdgcn_sched_barrier(0);
    PVMM(vrB, 3);

    // tail: commit V(t+1); barriers at the natural convergence point
    if (pf) {
      __syncthreads();
      WRITE_V();
      __syncthreads();
    }
  }

  // epilogue: normalize and store bf16 [s][h*128+d]
#pragma unroll
  for (int nn = 0; nn < 8; nn++)
#pragma unroll
    for (int r = 0; r < 4; r++) {
      const size_t row = qt * 128 + wave * 16 + lhi * 4 + r;
      const size_t col = (size_t)h * HD + nn * 16 + llo;
      aout[row * OUT_LD + col] = f2bf(o[nn][r] / lrow[r]);
    }
}

// ---------------- launch ----------------
extern "C" void kernel_launch(void* const* d_in, const int* in_sizes, int n_in,
                              void* d_out, int out_size, void* d_ws, size_t ws_size,
                              hipStream_t stream) {
  const float* tokens = (const float*)d_in[0];
  const float* wqkv   = (const float*)d_in[1];
  const float* wproj  = (const float*)d_in[2];
  float* out = (float*)d_out;

  short* tok_bf   = (short*)d_ws;
  short* wqkv_bf  = tok_bf   + (size_t)SEQ * HIDDEN;
  short* wproj_bf = wqkv_bf  + (size_t)QKV_LD * HIDDEN;
  short* qkv_bf   = wproj_bf + (size_t)HIDDEN * OUT_LD;
  short* attn_bf  = qkv_bf   + (size_t)SEQ * QKV_LD;

  cast_kernel<<<2048, 256, 0, stream>>>(tokens, tok_bf, SEQ * HIDDEN / 4);
  cast_kernel<<<2048, 256, 0, stream>>>(wqkv, wqkv_bf, QKV_LD * HIDDEN / 4);
  cast_kernel<<<2048, 256, 0, stream>>>(wproj, wproj_bf, HIDDEN * OUT_LD / 4);

  // QKV: 256x192 tiles -> 256 workgroups; NT=32 nt-cols, 4 per XCD
  gemm256b<short, 3><<<256, 512, 0, stream>>>(tok_bf, wqkv_bf, qkv_bf, SEQ, QKV_LD, HIDDEN, QKV_LD / 192);

  attn_fwd<<<dim3(NHEADS, SEQ / 128), 512, 0, stream>>>(qkv_bf, attn_bf);

  // proj: 256x128 tiles -> 256 workgroups; NT=32
  gemm256b<float, 2><<<256, 512, 0, stream>>>(attn_bf, wproj_bf, out, SEQ, OUT_LD, HIDDEN, OUT_LD / 128);
}

// Round 19
// 301.285 us; speedup vs baseline: 1.0119x; 1.0119x over previous
//
#include <hip/hip_runtime.h>
#include <hip/hip_bf16.h>
#include <stdint.h>

#define SEQ 2048
#define HIDDEN 4096
#define NHEADS 32
#define HD 128
#define QKV_LD 6144
#define OUT_LD 4096

typedef __attribute__((ext_vector_type(8))) short short8;
typedef __attribute__((ext_vector_type(4))) short short4v;
typedef __attribute__((ext_vector_type(4))) float f32x4;
typedef __attribute__((ext_vector_type(4))) int int4v;
typedef __attribute__((ext_vector_type(2))) unsigned int uint2v;
typedef __attribute__((ext_vector_type(4))) float float4v;

__device__ __forceinline__ short f2bf(float f) {
  uint32_t u = __builtin_bit_cast(uint32_t, f);
  u += 0x7fff + ((u >> 16) & 1);   // RNE
  return (short)(u >> 16);
}

// ---------------- cast fp32 -> bf16 ----------------
__global__ void cast_kernel(const float* __restrict__ in, short* __restrict__ out, int n4) {
  int stride = gridDim.x * blockDim.x;
  for (int i = blockIdx.x * blockDim.x + threadIdx.x; i < n4; i += stride) {
    float4v v = ((const float4v*)in)[i];
    short4v o;
    o[0] = f2bf(v[0]); o[1] = f2bf(v[1]); o[2] = f2bf(v[2]); o[3] = f2bf(v[3]);
    ((short4v*)out)[i] = o;
  }
}

// ======== 256 x (64*NBF) GEMM, 2-barrier K-tile: C = A[M][K] * B[N][K]^T ========
// 512 thr = 8 waves (2M x 4N). BK=64, double-buffered LDS, chunk^=row&7 swizzle.
// XCD map: each XCD owns NT/8 nt-columns x all 8 mt (mt-fast) -> B panel stays
// L2-resident; only A streams. At the ~900 TF 2-barrier-structure ceiling.
template <typename OT, int NBF>
__global__ __launch_bounds__(512, 2) void gemm256b(const short* __restrict__ A,
                                                   const short* __restrict__ B,
                                                   OT* __restrict__ C,
                                                   int M, int N, int K, int NT) {
  __shared__ __align__(16) short lds[32768 + NBF * 8192];  // A: 2x16384, B: 2x NBF*4096
  const int tid = threadIdx.x;
  const int w = tid >> 6, lane = tid & 63;
  const int wr = w >> 2, wc = w & 3;
  const int llo = lane & 15, lhi = lane >> 4;

  const int xcd = (int)blockIdx.x & 7;
  const int i = (int)blockIdx.x >> 3;
  const int nt = xcd * (NT >> 3) + (i >> 3);
  const int mt = i & 7;
  const size_t arow0 = (size_t)mt * 256, brow0 = (size_t)nt * (NBF * 64);
  const short* Ab = A + arow0 * K;
  const short* Bb = B + brow0 * K;

  f32x4 acc[8][NBF] = {};

  auto STAGE_A = [&](int kt, int j) {
    const int bufd = kt & 1;
    const int r0 = (j << 6) + (w << 3);
    const int row = r0 + (lane >> 3);
    const short* src = Ab + (size_t)row * K + (kt << 6) + (((lane & 7) ^ (row & 7)) << 3);
    short* dst = lds + (bufd << 14) + r0 * 64;
    __builtin_amdgcn_global_load_lds(
        (const __attribute__((address_space(1))) uint32_t*)src,
        (__attribute__((address_space(3))) uint32_t*)dst, 16, 0, 0);
  };
  auto STAGE_B = [&](int kt, int j) {
    const int bufd = kt & 1;
    const int r0 = (j << 6) + (w << 3);
    const int row = r0 + (lane >> 3);
    const short* src = Bb + (size_t)row * K + (kt << 6) + (((lane & 7) ^ (row & 7)) << 3);
    short* dst = lds + 32768 + bufd * (NBF << 12) + r0 * 64;
    __builtin_amdgcn_global_load_lds(
        (const __attribute__((address_space(1))) uint32_t*)src,
        (__attribute__((address_space(3))) uint32_t*)dst, 16, 0, 0);
  };
  auto STAGE = [&](int kt) {
#pragma unroll
    for (int j = 0; j < 4; j++) STAGE_A(kt, j);
#pragma unroll
    for (int j = 0; j < NBF; j++) STAGE_B(kt, j);
  };

  auto LDA = [&](int bufd, int m, int kk) -> short8 {
    const int row = (wr << 7) + (m << 4) + llo;
    const int ch = ((kk << 2) + lhi) ^ (row & 7);
    return *(const short8*)(lds + (bufd << 14) + row * 64 + (ch << 3));
  };
  auto LDB = [&](int bufd, int n, int kk) -> short8 {
    const int row = wc * (NBF << 4) + (n << 4) + llo;
    const int ch = ((kk << 2) + lhi) ^ (row & 7);
    return *(const short8*)(lds + 32768 + bufd * (NBF << 12) + row * 64 + (ch << 3));
  };

  STAGE(0);
  STAGE(1);
  if constexpr (NBF == 3) asm volatile("s_waitcnt vmcnt(7)" ::: "memory");
  else                    asm volatile("s_waitcnt vmcnt(6)" ::: "memory");
  __builtin_amdgcn_s_barrier();

  const int NKT = K >> 6;
  for (int kt = 0; kt < NKT; ++kt) {
    const int bufd = kt & 1;
    short8 b_[NBF][2];
#pragma unroll
    for (int n = 0; n < NBF; n++) { b_[n][0] = LDB(bufd, n, 0); b_[n][1] = LDB(bufd, n, 1); }
#pragma unroll
    for (int m = 0; m < 8; m++) {
      short8 a0 = LDA(bufd, m, 0);
      short8 a1 = LDA(bufd, m, 1);
#pragma unroll
      for (int n = 0; n < NBF; n++) {
        acc[m][n] = __builtin_amdgcn_mfma_f32_16x16x32_bf16(a0, b_[n][0], acc[m][n], 0, 0, 0);
        acc[m][n] = __builtin_amdgcn_mfma_f32_16x16x32_bf16(a1, b_[n][1], acc[m][n], 0, 0, 0);
      }
    }
    asm volatile("s_waitcnt lgkmcnt(0)" ::: "memory");
    __builtin_amdgcn_s_barrier();            // all waves done reading bufd
    if (kt + 2 < NKT) STAGE(kt + 2);         // refill this buffer
    if (kt + 1 < NKT) {
      if (kt + 2 < NKT) {
        if constexpr (NBF == 3) asm volatile("s_waitcnt vmcnt(7)" ::: "memory");
        else                    asm volatile("s_waitcnt vmcnt(6)" ::: "memory");
      } else {
        asm volatile("s_waitcnt vmcnt(0)" ::: "memory");
      }
      __builtin_amdgcn_s_barrier();          // next tile's data visible
    }
  }

#pragma unroll
  for (int m = 0; m < 8; m++)
#pragma unroll
    for (int n = 0; n < NBF; n++)
#pragma unroll
      for (int r = 0; r < 4; r++) {
        const size_t row = arow0 + (wr << 7) + (m << 4) + (lhi << 2) + r;
        const size_t col = brow0 + wc * (NBF << 4) + (n << 4) + llo;
        const float v = acc[m][n][r];
        if constexpr (sizeof(OT) == 2) C[row * N + col] = f2bf(v);
        else                           C[row * N + col] = v;
      }
}

// ---------------- flash attention, causal GQA, KVBLK=128 (session best) ----------------
// grid: (NHEADS, SEQ/128); block 512 = 8 waves x 16 q-rows; qt reversed.
// K double-buffered (2x32KB, DMA+swizzle); V single-buffered (32KB).
// V(t+1) loaded to regs at tile top (full-tile T14 flight), committed to Vsm
// AFTER PV(t); 2 barriers/tile at the natural convergence point.
__global__ __launch_bounds__(512) void attn_fwd(const short* __restrict__ qkv,
                                                short* __restrict__ aout) {
  const int qt = gridDim.y - 1 - blockIdx.y;          // heavy blocks first
  const int h = blockIdx.x;
  const int kvh = h >> 2, g = h & 3;
  const int tid = threadIdx.x;
  const int wave = tid >> 6, lane = tid & 63;
  const int lhi = lane >> 4, llo = lane & 15;

  __shared__ __align__(16) short Ksm[2][128 * 128];  // XOR-swizzled (chunk ^= row&7)
  __shared__ __align__(16) short Vsm[128 * 128];     // subtiled [k/4][d/16][4][16]
  __shared__ __align__(16) short Psm[8][16 * 136];   // per-wave P, stride 136

  const float scale2 = 0.08838834764831845f * 1.4426950408889634f;  // 1/sqrt(128)*log2e

  const int qrow = qt * 128 + wave * 16 + llo;
  const short* qbase = qkv + (size_t)qrow * QKV_LD + (kvh * 6 + g) * HD;
  short8 qf[4];
#pragma unroll
  for (int kk = 0; kk < 4; kk++) qf[kk] = *(const short8*)(qbase + kk * 32 + lhi * 8);

  f32x4 o[8] = {};
  float mrow[4], lrow[4];
#pragma unroll
  for (int r = 0; r < 4; r++) { mrow[r] = -1e30f; lrow[r] = 0.f; }

  const short* Kg = qkv + (kvh * 6 + 4) * HD;
  const short* Vg = qkv + (kvh * 6 + 5) * HD;

  auto STAGE_K = [&](int t, int buf) {               // 128x128 bf16 = 32KB = 32 calls
#pragma unroll
    for (int c = 0; c < 4; c++) {
      const int call = wave * 4 + c;
      const int row = call * 4 + lhi;
      const int sc = llo ^ (row & 7);
      __builtin_amdgcn_global_load_lds(
          (const __attribute__((address_space(1))) uint32_t*)(Kg + (size_t)(t * 128 + row) * QKV_LD + sc * 8),
          (__attribute__((address_space(3))) uint32_t*)(&Ksm[buf][0] + call * 512), 16, 0, 0);
    }
  };
  short8 vreg[4];
  auto LOAD_V = [&](int t) {                         // 128 rows -> 4 short8/thread
#pragma unroll
    for (int c = 0; c < 4; c++) {
      const int idx = c * 512 + tid;
      const int vr = idx >> 4;
      vreg[c] = *(const short8*)(Vg + (size_t)(t * 128 + vr) * QKV_LD + (idx & 15) * 8);
    }
  };
  auto WRITE_V = [&]() {
#pragma unroll
    for (int c = 0; c < 4; c++) {
      const int idx = c * 512 + tid;
      const int vr = idx >> 4, vc = idx & 15;
      *(short8*)(&Vsm[0] + ((vr >> 2) * 8 + (vc >> 1)) * 64 + (vr & 3) * 16 + (vc & 1) * 8) = vreg[c];
    }
  };

  const uint32_t vlane0 = (uint32_t)(uintptr_t)(__attribute__((address_space(3))) short*)(&Vsm[0])
                          + (uint32_t)(lhi * 2048 + llo * 8);

  // prologue: K(0) DMA + V(0) regs -> commit V(0); all visible after barrier
  STAGE_K(0, 0);
  LOAD_V(0);
  asm volatile("s_waitcnt vmcnt(0)" ::: "memory");
  WRITE_V();
  __syncthreads();

  const int ntiles = qt + 1;
  const int qpos0 = qt * 128 + wave * 16 + lhi * 4;   // + r
  for (int t = 0; t < ntiles; t++) {
    const int cur = t & 1, nxt = cur ^ 1;
    const bool pf = (t + 1 < ntiles);
    if (pf) { LOAD_V(t + 1); STAGE_K(t + 1, nxt); }  // in flight across whole tile

    // S = Q K^T from Ksm[cur] (128 cols)
    const short* Kc = &Ksm[cur][0];
    f32x4 s[8] = {};
#pragma unroll
    for (int n = 0; n < 8; n++) {
#pragma unroll
      for (int kk = 0; kk < 4; kk++) {
        const int krow = n * 16 + llo;
        const int ch = (kk * 4 + lhi) ^ (krow & 7);
        short8 kf = *(const short8*)(Kc + krow * 128 + ch * 8);
        s[n] = __builtin_amdgcn_mfma_f32_16x16x32_bf16(qf[kk], kf, s[n], 0, 0, 0);
      }
    }

    float sv[8][4];
    if (t == qt) {   // diagonal tile: causal mask (wave-uniform branch)
#pragma unroll
      for (int n = 0; n < 8; n++)
#pragma unroll
        for (int r = 0; r < 4; r++) {
          float x = s[n][r] * scale2;
          if (t * 128 + n * 16 + llo > qpos0 + r) x = -1e30f;
          sv[n][r] = x;
        }
    } else {
#pragma unroll
      for (int n = 0; n < 8; n++)
#pragma unroll
        for (int r = 0; r < 4; r++) sv[n][r] = s[n][r] * scale2;
    }

    // online softmax with defer-max
    float rm4[4];
#pragma unroll
    for (int r = 0; r < 4; r++) {
      float rm = sv[0][r];
#pragma unroll
      for (int n = 1; n < 8; n++) rm = fmaxf(rm, sv[n][r]);
#pragma unroll
      for (int msk = 1; msk < 16; msk <<= 1) rm = fmaxf(rm, __shfl_xor(rm, msk));
      rm4[r] = rm;
    }
    bool need = false;
#pragma unroll
    for (int r = 0; r < 4; r++) need = need || (rm4[r] > mrow[r] + 8.0f);
    if (__any(need)) {
#pragma unroll
      for (int r = 0; r < 4; r++) {
        const float mnew = fmaxf(mrow[r], rm4[r]);
        const float a = exp2f(mrow[r] - mnew);
        mrow[r] = mnew;
        lrow[r] *= a;
#pragma unroll
        for (int nn = 0; nn < 8; nn++) o[nn][r] *= a;
      }
    }
#pragma unroll
    for (int r = 0; r < 4; r++) {
      float rs = 0.f;
#pragma unroll
      for (int n = 0; n < 8; n++) {
        float p = exp2f(sv[n][r] - mrow[r]);
        sv[n][r] = p;
        rs += p;
      }
#pragma unroll
      for (int msk = 1; msk < 16; msk <<= 1) rs += __shfl_xor(rs, msk);
      lrow[r] += rs;
    }

    // P -> LDS (wave-local), A-frags back
    short* P = &Psm[wave][0];
#pragma unroll
    for (int n = 0; n < 8; n++)
#pragma unroll
      for (int r = 0; r < 4; r++)
        P[(lhi * 4 + r) * 136 + n * 16 + llo] = f2bf(sv[n][r]);
    short8 pa[4];
#pragma unroll
    for (int ks = 0; ks < 4; ks++)
      pa[ks] = *(const short8*)(P + llo * 136 + ks * 32 + lhi * 8);

    // PV from Vsm (holds V(t), committed at the end of tile t-1)
#pragma unroll
    for (int ks = 0; ks < 4; ks++) {
      uint2v vr_[8][2];
#pragma unroll
      for (int nn = 0; nn < 8; nn++)
#pragma unroll
        for (int hh = 0; hh < 2; hh++) {
          asm volatile("ds_read_b64_tr_b16 %0, %1 offset:%2"
                       : "=v"(vr_[nn][hh])
                       : "v"(vlane0), "i"(ks * 8192 + hh * 1024 + nn * 128));
        }
      asm volatile("s_waitcnt lgkmcnt(0)" ::: "memory");
      __builtin_amdgcn_sched_barrier(0);
#pragma unroll
      for (int nn = 0; nn < 8; nn++) {
        int4v tv;
        tv[0] = (int)vr_[nn][0][0]; tv[1] = (int)vr_[nn][0][1];
        tv[2] = (int)vr_[nn][1][0]; tv[3] = (int)vr_[nn][1][1];
        o[nn] = __builtin_amdgcn_mfma_f32_16x16x32_bf16(pa[ks], __builtin_bit_cast(short8, tv), o[nn], 0, 0, 0);
      }
    }

    // tail: commit V(t+1); barriers at the natural convergence point
    if (pf) {
      __syncthreads();
      WRITE_V();
      __syncthreads();
    }
  }

  // epilogue: normalize and store bf16 [s][h*128+d]
#pragma unroll
  for (int nn = 0; nn < 8; nn++)
#pragma unroll
    for (int r = 0; r < 4; r++) {
      const size_t row = qt * 128 + wave * 16 + lhi * 4 + r;
      const size_t col = (size_t)h * HD + nn * 16 + llo;
      aout[row * OUT_LD + col] = f2bf(o[nn][r] / lrow[r]);
    }
}

// ---------------- launch ----------------
extern "C" void kernel_launch(void* const* d_in, const int* in_sizes, int n_in,
                              void* d_out, int out_size, void* d_ws, size_t ws_size,
                              hipStream_t stream) {
  const float* tokens = (const float*)d_in[0];
  const float* wqkv   = (const float*)d_in[1];
  const float* wproj  = (const float*)d_in[2];
  float* out = (float*)d_out;

  short* tok_bf   = (short*)d_ws;
  short* wqkv_bf  = tok_bf   + (size_t)SEQ * HIDDEN;
  short* wproj_bf = wqkv_bf  + (size_t)QKV_LD * HIDDEN;
  short* qkv_bf   = wproj_bf + (size_t)HIDDEN * OUT_LD;
  short* attn_bf  = qkv_bf   + (size_t)SEQ * QKV_LD;

  cast_kernel<<<2048, 256, 0, stream>>>(tokens, tok_bf, SEQ * HIDDEN / 4);
  cast_kernel<<<2048, 256, 0, stream>>>(wqkv, wqkv_bf, QKV_LD * HIDDEN / 4);
  cast_kernel<<<2048, 256, 0, stream>>>(wproj, wproj_bf, HIDDEN * OUT_LD / 4);

  // QKV: 256x192 tiles -> 256 workgroups; NT=32 nt-cols, 4 per XCD
  gemm256b<short, 3><<<256, 512, 0, stream>>>(tok_bf, wqkv_bf, qkv_bf, SEQ, QKV_LD, HIDDEN, QKV_LD / 192);

  attn_fwd<<<dim3(NHEADS, SEQ / 128), 512, 0, stream>>>(qkv_bf, attn_bf);

  // proj: 256x128 tiles -> 256 workgroups; NT=32
  gemm256b<float, 2><<<256, 512, 0, stream>>>(attn_bf, wproj_bf, out, SEQ, OUT_LD, HIDDEN, OUT_LD / 128);
}